// Round 1
// baseline (18379.095 us; speedup 1.0000x reference)
//
#include <hip/hip_runtime.h>

// ---------------------------------------------------------------------------
// DeconvCG: 100 CG iterations solving (K^T K + sum w_i^2 G_i^T G_i) x = K^T y
// Persistent-kernel design: 192 blocks (3ch x 8x8 tiles of 64x64), 512 thr.
// x, r, Ap live in registers; p-halo + conv intermediate staged in LDS.
// 2 hand-rolled device-scope grid barriers per iteration.
// ---------------------------------------------------------------------------

static constexpr int H = 512, W = 512, CCH = 3;
static constexpr int NPIX = CCH * H * W;          // 786432
static constexpr int TDIM = 64;                   // owned tile (square)
static constexpr int RAD = 5;                     // 11x11 radius
static constexpr int HALO = 10;                   // two chained 11x11 convs
static constexpr int PR = TDIM + 2 * HALO;        // 84  (p region)
static constexpr int PSTR = PR + 1;               // 85  (odd stride, bank spread)
static constexpr int TR = TDIM + 2 * RAD;         // 74  (t region)
static constexpr int TSTR = TR + 1;               // 75
static constexpr int NBLK = CCH * 8 * 8;          // 192
static constexpr int NTHR = 512;
static constexpr int NITER = 100;

// ---------------- device-scope grid barrier (192 co-resident blocks) -------
__device__ __forceinline__ void gsync(unsigned* bar, int tid)
{
    __syncthreads();
    __threadfence();   // agent-scope release: prior global writes visible device-wide
    if (tid == 0) {
        unsigned g = __hip_atomic_load(&bar[1], __ATOMIC_RELAXED, __HIP_MEMORY_SCOPE_AGENT);
        unsigned a = __hip_atomic_fetch_add(&bar[0], 1u, __ATOMIC_ACQ_REL, __HIP_MEMORY_SCOPE_AGENT);
        if (a == (unsigned)(NBLK - 1)) {
            __hip_atomic_store(&bar[0], 0u, __ATOMIC_RELAXED, __HIP_MEMORY_SCOPE_AGENT);
            __hip_atomic_store(&bar[1], g + 1u, __ATOMIC_RELEASE, __HIP_MEMORY_SCOPE_AGENT);
        } else {
            while (__hip_atomic_load(&bar[1], __ATOMIC_ACQUIRE, __HIP_MEMORY_SCOPE_AGENT) == g)
                __builtin_amdgcn_s_sleep(1);
        }
    }
    __syncthreads();
    __threadfence();   // acquire side for all threads
}

// ---------------- block reductions (deterministic) -------------------------
__device__ __forceinline__ float block_reduce0(float v, float* red, int tid)
{
    __syncthreads();   // protect red[] reuse from previous call
    #pragma unroll
    for (int m = 32; m; m >>= 1) v += __shfl_xor(v, m, 64);
    if ((tid & 63) == 0) red[tid >> 6] = v;
    __syncthreads();
    float s = 0.f;
    if (tid == 0) {
        #pragma unroll
        for (int i = 0; i < NTHR / 64; ++i) s += red[i];
    }
    return s;          // valid on tid 0 only
}

__device__ __forceinline__ float allreduce_part(const float* part, float* red, float* bc, int tid)
{
    float v = (tid < NBLK) ? part[tid] : 0.f;
    float s = block_reduce0(v, red, tid);
    if (tid == 0) *bc = s;
    __syncthreads();
    return *bc;        // bitwise-identical in every block (same tree, same inputs)
}

// ---------------- 11x11 convs ----------------------------------------------
// forward (correlation with k): t(ry,rx) = sum_{a,b} P[ry+a][rx+b] * k[a][b]
__device__ __forceinline__ void conv_fwd_phase(const float* __restrict__ kern,
                                               const float* __restrict__ P_,
                                               float* __restrict__ T_,
                                               int by0, int bx0, int tid)
{
    for (int seg = tid; seg < TR * 10; seg += NTHR) {
        int ry  = seg / 10;
        int rx0 = (seg - ry * 10) << 3;
        int gy  = by0 - RAD + ry;
        bool rowIn = (gy >= 0 && gy < H);
        float acc[8];
        #pragma unroll
        for (int j = 0; j < 8; ++j) acc[j] = 0.f;
        for (int a = 0; a < 11; ++a) {
            const float* row = P_ + (ry + a) * PSTR + rx0;
            float v[18];
            #pragma unroll
            for (int b = 0; b < 18; ++b) v[b] = row[b];
            #pragma unroll
            for (int b = 0; b < 11; ++b) {
                float kw = kern[a * 11 + b];
                #pragma unroll
                for (int j = 0; j < 8; ++j) acc[j] = fmaf(v[b + j], kw, acc[j]);
            }
        }
        #pragma unroll
        for (int j = 0; j < 8; ++j) {
            int rx = rx0 + j;
            if (rx < TR) {
                int gx = bx0 - RAD + rx;
                bool in = rowIn && gx >= 0 && gx < W;
                T_[ry * TSTR + rx] = in ? acc[j] : 0.f;   // zero outside image (truncation)
            }
        }
    }
}

// flipped (conv with flip(k)): acc += sum_{a,b} src[row0+a][col0+b+j] * k[10-a][10-b]
__device__ __forceinline__ void conv11_flip_acc(const float* __restrict__ src, int stride,
                                                int row0, int col0,
                                                const float* __restrict__ kern,
                                                float acc[8])
{
    for (int a = 0; a < 11; ++a) {
        const float* row = src + (row0 + a) * stride + col0;
        float v[18];
        #pragma unroll
        for (int b = 0; b < 18; ++b) v[b] = row[b];
        #pragma unroll
        for (int b = 0; b < 11; ++b) {
            float kw = kern[(10 - a) * 11 + (10 - b)];
            #pragma unroll
            for (int j = 0; j < 8; ++j) acc[j] = fmaf(v[b + j], kw, acc[j]);
        }
    }
}

// ---------------- regularizer term -----------------------------------------
// interior: single 5x5 stencil CB = w0^2*autocorr(g0)+w1^2*autocorr(g1)
// border:   exact two-pass with intermediate truncation at image edge
__device__ __forceinline__ void reg_acc(const float* __restrict__ P_,
                                        const float* __restrict__ CB_,
                                        const float* __restrict__ gk,
                                        float w0sq, float w1sq,
                                        int oy, int ox0, int gy, int gx0,
                                        float acc[8])
{
    bool interior = (gy >= 1 && gy < H - 1 && gx0 >= 1 && gx0 <= W - 9);
    if (interior) {
        for (int a = 0; a < 5; ++a) {
            const float* row = P_ + (oy + 8 + a) * PSTR + ox0 + 8;
            float v[12];
            #pragma unroll
            for (int b = 0; b < 12; ++b) v[b] = row[b];
            #pragma unroll
            for (int b = 0; b < 5; ++b) {
                float cb = CB_[a * 5 + b];
                #pragma unroll
                for (int j = 0; j < 8; ++j) acc[j] = fmaf(v[b + j], cb, acc[j]);
            }
        }
    } else {
        for (int j = 0; j < 8; ++j) {
            int gx = gx0 + j;
            float racc = 0.f;
            for (int dy = -1; dy <= 1; ++dy)
                for (int dx = -1; dx <= 1; ++dx) {
                    int qy = gy + dy, qx = gx + dx;
                    if (qy >= 0 && qy < H && qx >= 0 && qx < W) {
                        float u0 = 0.f, u1 = 0.f;
                        int pr0 = oy + 10 + dy - 1, pc0 = ox0 + j + 10 + dx - 1;
                        for (int sy = 0; sy < 3; ++sy)
                            for (int sx = 0; sx < 3; ++sx) {
                                float pv = P_[(pr0 + sy) * PSTR + pc0 + sx];
                                u0 = fmaf(pv, gk[sy * 3 + sx], u0);
                                u1 = fmaf(pv, gk[9 + sy * 3 + sx], u1);
                            }
                        racc += w0sq * gk[(1 - dy) * 3 + (1 - dx)] * u0
                              + w1sq * gk[9 + (1 - dy) * 3 + (1 - dx)] * u1;
                    }
                }
            acc[j] += racc;
        }
    }
}

// ---------------- init barrier state ---------------------------------------
__global__ void bar_init(unsigned* bar) { bar[0] = 0u; bar[1] = 0u; }

// ---------------- main persistent kernel -----------------------------------
__global__ void __launch_bounds__(NTHR)
deconv_cg(const float* __restrict__ img, const float* __restrict__ kern,
          const float* __restrict__ wts, const float* __restrict__ gk,
          float* __restrict__ out, float* __restrict__ ws)
{
    __shared__ float P[PR * PSTR + 32];   // p' (halo region), zero outside image
    __shared__ float T[TR * TSTR + 32];   // intermediate conv, zero outside image
    __shared__ float CB[25];
    __shared__ float red[NTHR / 64];
    __shared__ float bc;

    const int tid = threadIdx.x;
    const int bid = blockIdx.x;
    const int ch  = bid / 64;
    const int tt  = bid - ch * 64;
    const int by0 = (tt >> 3) * TDIM;
    const int bx0 = (tt & 7) * TDIM;

    const float* imgc = img + ch * H * W;
    float* partA = ws;                // [0,192)
    float* partB = ws + 256;          // [256,448)
    unsigned* bar = (unsigned*)(ws + 512);
    float* Pg = ws + 1024;            // p array
    float* Rg = Pg + NPIX;            // r array
    float* pc = Pg + ch * H * W;
    float* rc = Rg + ch * H * W;

    const float w0 = wts[0], w1 = wts[1];
    const float w0sq = w0 * w0, w1sq = w1 * w1;

    // combined 5x5 reg kernel: CB[t] = sum_a g[a]*g[a+t], weighted
    if (tid < 25) {
        int ty = tid / 5 - 2, tx = tid % 5 - 2;
        float s = 0.f;
        for (int ay = 0; ay < 3; ++ay)
            for (int ax = 0; ax < 3; ++ax) {
                int by_ = ay + ty, bx_ = ax + tx;
                if (by_ >= 0 && by_ < 3 && bx_ >= 0 && bx_ < 3)
                    s += w0sq * gk[ay * 3 + ax] * gk[by_ * 3 + bx_]
                       + w1sq * gk[9 + ay * 3 + ax] * gk[9 + by_ * 3 + bx_];
            }
        CB[tid] = s;
    }

    // owned-pixel mapping: thread -> 8 consecutive-x pixels of one row
    const int oy  = tid >> 3;
    const int ox0 = (tid & 7) << 3;
    const int gy  = by0 + oy;
    const int gx0 = bx0 + ox0;

    float xr[8], rr[8];

    // ================= init: r0 = K^T y - A*x0, x0 = image, p0 = r0 ========
    for (int idx = tid; idx < PR * PR; idx += NTHR) {
        int py = idx / PR, px = idx - py * PR;
        int iy = by0 - HALO + py, ix = bx0 - HALO + px;
        float v = 0.f;
        if (iy >= 0 && iy < H && ix >= 0 && ix < W) v = imgc[iy * W + ix];
        P[py * PSTR + px] = v;
    }
    __syncthreads();
    conv_fwd_phase(kern, P, T, by0, bx0, tid);
    __syncthreads();
    {
        float accA[8], accB[8];
        #pragma unroll
        for (int j = 0; j < 8; ++j) { accA[j] = 0.f; accB[j] = 0.f; }
        conv11_flip_acc(T, TSTR, oy, ox0, kern, accA);            // K^T K x0
        conv11_flip_acc(P, PSTR, oy + 5, ox0 + 5, kern, accB);    // b = K^T y
        reg_acc(P, CB, gk, w0sq, w1sq, oy, ox0, gy, gx0, accA);   // + reg x0
        float dr = 0.f;
        #pragma unroll
        for (int j = 0; j < 8; ++j) {
            float r0 = accB[j] - accA[j];
            rr[j] = r0;
            xr[j] = P[(oy + HALO) * PSTR + ox0 + HALO + j];       // x0 = image
            int gi = gy * W + gx0 + j;
            rc[gi] = r0;
            pc[gi] = r0;
            dr = fmaf(r0, r0, dr);
        }
        float s = block_reduce0(dr, red, tid);
        if (tid == 0) partB[bid] = s;
    }
    gsync(bar, tid);
    float rTr  = allreduce_part(partB, red, &bc, tid);
    float beta = 0.f;

    // ================= CG main loop ========================================
    for (int it = 0; it < NITER; ++it) {
        // phase 1: p' = r + beta*p (redundant on halo region; LDS only)
        for (int idx = tid; idx < PR * PR; idx += NTHR) {
            int py = idx / PR, px = idx - py * PR;
            int iy = by0 - HALO + py, ix = bx0 - HALO + px;
            float v = 0.f;
            if (iy >= 0 && iy < H && ix >= 0 && ix < W) {
                int gi = iy * W + ix;
                v = fmaf(beta, pc[gi], rc[gi]);
            }
            P[py * PSTR + px] = v;
        }
        __syncthreads();

        // phase 2: t = conv(p', k) on T+5 region
        conv_fwd_phase(kern, P, T, by0, bx0, tid);
        __syncthreads();

        // phase 3: Ap on owned tile, partial dot(p,Ap)
        float Ap[8], pw[8];
        {
            float acc[8];
            #pragma unroll
            for (int j = 0; j < 8; ++j) acc[j] = 0.f;
            conv11_flip_acc(T, TSTR, oy, ox0, kern, acc);
            reg_acc(P, CB, gk, w0sq, w1sq, oy, ox0, gy, gx0, acc);
            float dp = 0.f;
            #pragma unroll
            for (int j = 0; j < 8; ++j) {
                Ap[j] = acc[j];
                pw[j] = P[(oy + HALO) * PSTR + ox0 + HALO + j];
                dp = fmaf(pw[j], Ap[j], dp);
            }
            float s = block_reduce0(dp, red, tid);
            if (tid == 0) partA[bid] = s;
        }
        gsync(bar, tid);   // S1: pAp ready; also: all phase-1 reads of pc/rc done

        // phase 4: alpha, update x (regs), r (regs + global), write new p
        float pAp   = allreduce_part(partA, red, &bc, tid);
        float alpha = rTr / pAp;
        {
            float dr = 0.f;
            #pragma unroll
            for (int j = 0; j < 8; ++j) {
                xr[j] = fmaf(alpha, pw[j], xr[j]);
                rr[j] = fmaf(-alpha, Ap[j], rr[j]);
                int gi = gy * W + gx0 + j;
                rc[gi] = rr[j];
                pc[gi] = pw[j];
                dr = fmaf(rr[j], rr[j], dr);
            }
            float s = block_reduce0(dr, red, tid);
            if (tid == 0) partB[bid] = s;
        }
        gsync(bar, tid);   // S2: new r/p visible, rr sum ready

        float s = allreduce_part(partB, red, &bc, tid);
        beta = s / rTr;
        rTr  = s;
    }

    // write x
    float* outc = out + ch * H * W;
    #pragma unroll
    for (int j = 0; j < 8; ++j) outc[gy * W + gx0 + j] = xr[j];
}

// ---------------------------------------------------------------------------
extern "C" void kernel_launch(void* const* d_in, const int* in_sizes, int n_in,
                              void* d_out, int out_size, void* d_ws, size_t ws_size,
                              hipStream_t stream)
{
    (void)in_sizes; (void)n_in; (void)out_size; (void)ws_size;
    const float* img  = (const float*)d_in[0];   // [3,512,512]
    const float* kern = (const float*)d_in[1];   // [11,11]
    const float* wts  = (const float*)d_in[2];   // [2]
    const float* gk   = (const float*)d_in[3];   // [2,3,3]
    float* out = (float*)d_out;
    float* ws  = (float*)d_ws;
    unsigned* bar = (unsigned*)(ws + 512);

    bar_init<<<1, 1, 0, stream>>>(bar);
    deconv_cg<<<dim3(NBLK), dim3(NTHR), 0, stream>>>(img, kern, wts, gk, out, ws);
}

// Round 2
// 4831.577 us; speedup vs baseline: 3.8040x; 3.8040x over previous
//
#include <hip/hip_runtime.h>

// ---------------------------------------------------------------------------
// DeconvCG: 100 CG iterations solving (K^T K + sum w_i^2 G_i^T G_i) x = K^T y
// Persistent-kernel design: 192 blocks (3ch x 8x8 tiles of 64x64), 512 thr.
// x, r, p live in registers; p-halo + conv intermediate staged in LDS.
// Cross-block traffic = 10-wide border strips only, via relaxed agent-scope
// atomics (L3-coherent, no cache-invalidate fences). Grid barrier fused with
// the dot-product allreduce: tagged-slot all-to-all, double-buffered by parity.
// ---------------------------------------------------------------------------

static constexpr int H = 512, W = 512, CCH = 3;
static constexpr int NPIX = CCH * H * W;          // 786432
static constexpr int TDIM = 64;                   // owned tile (square)
static constexpr int RAD = 5;                     // 11x11 radius
static constexpr int HALO = 10;                   // two chained 11x11 convs
static constexpr int PR = TDIM + 2 * HALO;        // 84  (p region)
static constexpr int PSTR = PR + 1;               // 85
static constexpr int TR = TDIM + 2 * RAD;         // 74  (t region)
static constexpr int TSTR = TR + 1;               // 75
static constexpr int NBLK = CCH * 8 * 8;          // 192
static constexpr int NTHR = 512;
static constexpr int NITER = 100;

// ---------------- block reduction (deterministic) --------------------------
__device__ __forceinline__ float block_reduce0(float v, float* red, int tid)
{
    __syncthreads();   // protect red[] reuse from previous call
    #pragma unroll
    for (int m = 32; m; m >>= 1) v += __shfl_xor(v, m, 64);
    if ((tid & 63) == 0) red[tid >> 6] = v;
    __syncthreads();
    float s = 0.f;
    if (tid == 0) {
        #pragma unroll
        for (int i = 0; i < NTHR / 64; ++i) s += red[i];
    }
    return s;          // valid on tid 0 only
}

// ---------------- fused grid-barrier + allreduce ---------------------------
// Each block posts (seq<<32)|bits(partial) to its slot (parity-double-buffered),
// polls all NBLK slots for tag==seq, sums deterministically. Relaxed agent
// atomics only -> no L2 writeback/invalidate. Prior global stores are drained
// (vmcnt 0 per wave) before the slot post, so strip data is L3-visible first.
__device__ __forceinline__ float allreduce_bar(unsigned long long* slots, unsigned seq,
                                               float thread_partial,
                                               float* red, float* bc, int tid, int bid)
{
    float part = block_reduce0(thread_partial, red, tid);   // valid on tid 0
    asm volatile("s_waitcnt vmcnt(0)" ::: "memory");        // drain my strip stores
    __syncthreads();                                        // all waves drained
    unsigned long long* buf = slots + (size_t)(seq & 1u) * 256;
    if (tid == 0) {
        unsigned long long u = ((unsigned long long)seq << 32)
                             | (unsigned long long)__float_as_uint(part);
        __hip_atomic_store(&buf[bid], u, __ATOMIC_RELAXED, __HIP_MEMORY_SCOPE_AGENT);
    }
    float mine = 0.f;
    if (tid < NBLK) {
        unsigned long long v;
        for (;;) {
            v = __hip_atomic_load(&buf[tid], __ATOMIC_RELAXED, __HIP_MEMORY_SCOPE_AGENT);
            if ((unsigned)(v >> 32) == seq) break;
            __builtin_amdgcn_s_sleep(1);
        }
        mine = __uint_as_float((unsigned)v);
    }
    float s = block_reduce0(mine, red, tid);                // same tree everywhere
    if (tid == 0) *bc = s;
    __syncthreads();
    return *bc;        // bitwise-identical in every block
}

// ---------------- 11x11 convs ----------------------------------------------
// forward (correlation with k): t(ry,rx) = sum_{a,b} P[ry+a][rx+b] * k[a][b]
__device__ __forceinline__ void conv_fwd_phase(const float* __restrict__ kern,
                                               const float* __restrict__ P_,
                                               float* __restrict__ T_,
                                               int by0, int bx0, int tid)
{
    for (int seg = tid; seg < TR * 10; seg += NTHR) {
        int ry  = seg / 10;
        int rx0 = (seg - ry * 10) << 3;
        int gy  = by0 - RAD + ry;
        bool rowIn = (gy >= 0 && gy < H);
        float acc[8];
        #pragma unroll
        for (int j = 0; j < 8; ++j) acc[j] = 0.f;
        for (int a = 0; a < 11; ++a) {
            const float* row = P_ + (ry + a) * PSTR + rx0;
            float v[18];
            #pragma unroll
            for (int b = 0; b < 18; ++b) v[b] = row[b];
            #pragma unroll
            for (int b = 0; b < 11; ++b) {
                float kw = kern[a * 11 + b];
                #pragma unroll
                for (int j = 0; j < 8; ++j) acc[j] = fmaf(v[b + j], kw, acc[j]);
            }
        }
        #pragma unroll
        for (int j = 0; j < 8; ++j) {
            int rx = rx0 + j;
            if (rx < TR) {
                int gx = bx0 - RAD + rx;
                bool in = rowIn && gx >= 0 && gx < W;
                T_[ry * TSTR + rx] = in ? acc[j] : 0.f;   // zero outside image
            }
        }
    }
}

// flipped (conv with flip(k)): acc += sum_{a,b} src[row0+a][col0+b+j] * k[10-a][10-b]
__device__ __forceinline__ void conv11_flip_acc(const float* __restrict__ src, int stride,
                                                int row0, int col0,
                                                const float* __restrict__ kern,
                                                float acc[8])
{
    for (int a = 0; a < 11; ++a) {
        const float* row = src + (row0 + a) * stride + col0;
        float v[18];
        #pragma unroll
        for (int b = 0; b < 18; ++b) v[b] = row[b];
        #pragma unroll
        for (int b = 0; b < 11; ++b) {
            float kw = kern[(10 - a) * 11 + (10 - b)];
            #pragma unroll
            for (int j = 0; j < 8; ++j) acc[j] = fmaf(v[b + j], kw, acc[j]);
        }
    }
}

// ---------------- regularizer term -----------------------------------------
__device__ __forceinline__ void reg_acc(const float* __restrict__ P_,
                                        const float* __restrict__ CB_,
                                        const float* __restrict__ gk,
                                        float w0sq, float w1sq,
                                        int oy, int ox0, int gy, int gx0,
                                        float acc[8])
{
    bool interior = (gy >= 1 && gy < H - 1 && gx0 >= 1 && gx0 <= W - 9);
    if (interior) {
        for (int a = 0; a < 5; ++a) {
            const float* row = P_ + (oy + 8 + a) * PSTR + ox0 + 8;
            float v[12];
            #pragma unroll
            for (int b = 0; b < 12; ++b) v[b] = row[b];
            #pragma unroll
            for (int b = 0; b < 5; ++b) {
                float cb = CB_[a * 5 + b];
                #pragma unroll
                for (int j = 0; j < 8; ++j) acc[j] = fmaf(v[b + j], cb, acc[j]);
            }
        }
    } else {
        for (int j = 0; j < 8; ++j) {
            int gx = gx0 + j;
            float racc = 0.f;
            for (int dy = -1; dy <= 1; ++dy)
                for (int dx = -1; dx <= 1; ++dx) {
                    int qy = gy + dy, qx = gx + dx;
                    if (qy >= 0 && qy < H && qx >= 0 && qx < W) {
                        float u0 = 0.f, u1 = 0.f;
                        int pr0 = oy + 10 + dy - 1, pc0 = ox0 + j + 10 + dx - 1;
                        for (int sy = 0; sy < 3; ++sy)
                            for (int sx = 0; sx < 3; ++sx) {
                                float pv = P_[(pr0 + sy) * PSTR + pc0 + sx];
                                u0 = fmaf(pv, gk[sy * 3 + sx], u0);
                                u1 = fmaf(pv, gk[9 + sy * 3 + sx], u1);
                            }
                        racc += w0sq * gk[(1 - dy) * 3 + (1 - dx)] * u0
                              + w1sq * gk[9 + (1 - dy) * 3 + (1 - dx)] * u1;
                    }
                }
            acc[j] += racc;
        }
    }
}

// ---------------- slot init (fresh tags each call) -------------------------
__global__ void slot_init(unsigned long long* slots) { slots[threadIdx.x] = 0ull; }

// ---------------- main persistent kernel -----------------------------------
__global__ void __launch_bounds__(NTHR)
deconv_cg(const float* __restrict__ img, const float* __restrict__ kern,
          const float* __restrict__ wts, const float* __restrict__ gk,
          float* __restrict__ out, float* __restrict__ ws)
{
    __shared__ float P[PR * PSTR + 32];   // p (halo region), zero outside image
    __shared__ float T[TR * TSTR + 32];   // intermediate conv
    __shared__ float CB[25];
    __shared__ float red[NTHR / 64];
    __shared__ float bc;

    const int tid = threadIdx.x;
    const int bid = blockIdx.x;
    const int ch  = bid / 64;
    const int tt  = bid - ch * 64;
    const int by0 = (tt >> 3) * TDIM;
    const int bx0 = (tt & 7) * TDIM;

    const float* imgc = img + ch * H * W;
    unsigned long long* slots = (unsigned long long*)ws;            // [2][256]
    unsigned long long* Hg    = (unsigned long long*)ws + 512;      // packed {r,p}
    unsigned long long* Hc    = Hg + (size_t)ch * H * W;

    const float w0 = wts[0], w1 = wts[1];
    const float w0sq = w0 * w0, w1sq = w1 * w1;

    // combined 5x5 reg kernel (autocorrelation), for interior pixels
    if (tid < 25) {
        int ty = tid / 5 - 2, tx = tid % 5 - 2;
        float s = 0.f;
        for (int ay = 0; ay < 3; ++ay)
            for (int ax = 0; ax < 3; ++ax) {
                int by_ = ay + ty, bx_ = ax + tx;
                if (by_ >= 0 && by_ < 3 && bx_ >= 0 && bx_ < 3)
                    s += w0sq * gk[ay * 3 + ax] * gk[by_ * 3 + bx_]
                       + w1sq * gk[9 + ay * 3 + ax] * gk[9 + by_ * 3 + bx_];
            }
        CB[tid] = s;
    }

    // owned-pixel mapping: thread -> 8 consecutive-x pixels of one row
    const int oy  = tid >> 3;
    const int ox0 = (tid & 7) << 3;
    const int gy  = by0 + oy;
    const int gx0 = bx0 + ox0;
    // which of my 8 pixels lie in the 10-wide published border strip
    bool strip[8];
    #pragma unroll
    for (int j = 0; j < 8; ++j) {
        int ox = ox0 + j;
        strip[j] = (oy < HALO) | (oy >= TDIM - HALO) | (ox < HALO) | (ox >= TDIM - HALO);
    }

    float xr[8], rr[8], pr[8];

    // ================= init: r0 = K^T y - A*x0, x0 = image, p0 = r0 ========
    for (int idx = tid; idx < PR * PR; idx += NTHR) {
        int py = idx / PR, px = idx - py * PR;
        int iy = by0 - HALO + py, ix = bx0 - HALO + px;
        float v = 0.f;
        if (iy >= 0 && iy < H && ix >= 0 && ix < W) v = imgc[iy * W + ix];
        P[py * PSTR + px] = v;
    }
    __syncthreads();
    conv_fwd_phase(kern, P, T, by0, bx0, tid);
    __syncthreads();
    float rTr, beta = 0.f;
    {
        float accA[8], accB[8];
        #pragma unroll
        for (int j = 0; j < 8; ++j) { accA[j] = 0.f; accB[j] = 0.f; }
        conv11_flip_acc(T, TSTR, oy, ox0, kern, accA);            // K^T K x0
        conv11_flip_acc(P, PSTR, oy + 5, ox0 + 5, kern, accB);    // b = K^T y
        reg_acc(P, CB, gk, w0sq, w1sq, oy, ox0, gy, gx0, accA);   // + reg x0
        float dr = 0.f;
        #pragma unroll
        for (int j = 0; j < 8; ++j) {
            float r0 = accB[j] - accA[j];
            rr[j] = r0;
            pr[j] = r0;
            xr[j] = P[(oy + HALO) * PSTR + ox0 + HALO + j];       // x0 = image
            if (strip[j]) {
                unsigned long long u = (unsigned long long)__float_as_uint(r0)
                                     | ((unsigned long long)__float_as_uint(r0) << 32);
                __hip_atomic_store(&Hc[gy * W + gx0 + j], u,
                                   __ATOMIC_RELAXED, __HIP_MEMORY_SCOPE_AGENT);
            }
            dr = fmaf(r0, r0, dr);
        }
        rTr = allreduce_bar(slots, 1u, dr, red, &bc, tid, bid);
    }

    // ================= CG main loop ========================================
    for (int it = 0; it < NITER; ++it) {
        // phase 1: p_new = r + beta*p. Owned tile from registers; frame from
        // neighbors' published strips (L3-coherent relaxed atomics).
        #pragma unroll
        for (int j = 0; j < 8; ++j) pr[j] = fmaf(beta, pr[j], rr[j]);
        for (int idx = tid; idx < PR * PR; idx += NTHR) {
            int py = idx / PR, px = idx - py * PR;
            if (py >= HALO && py < HALO + TDIM && px >= HALO && px < HALO + TDIM)
                continue;                                   // owned, from regs
            int iy = by0 - HALO + py, ix = bx0 - HALO + px;
            float v = 0.f;
            if (iy >= 0 && iy < H && ix >= 0 && ix < W) {
                unsigned long long u = __hip_atomic_load(&Hc[iy * W + ix],
                                       __ATOMIC_RELAXED, __HIP_MEMORY_SCOPE_AGENT);
                float hr = __uint_as_float((unsigned)u);
                float hp = __uint_as_float((unsigned)(u >> 32));
                v = fmaf(beta, hp, hr);
            }
            P[py * PSTR + px] = v;
        }
        #pragma unroll
        for (int j = 0; j < 8; ++j)
            P[(oy + HALO) * PSTR + ox0 + HALO + j] = pr[j];
        __syncthreads();

        // phase 2: t = conv(p, k)
        conv_fwd_phase(kern, P, T, by0, bx0, tid);
        __syncthreads();

        // phase 3: Ap on owned tile, dot(p,Ap)
        float Ap[8];
        float dp = 0.f;
        {
            float acc[8];
            #pragma unroll
            for (int j = 0; j < 8; ++j) acc[j] = 0.f;
            conv11_flip_acc(T, TSTR, oy, ox0, kern, acc);
            reg_acc(P, CB, gk, w0sq, w1sq, oy, ox0, gy, gx0, acc);
            #pragma unroll
            for (int j = 0; j < 8; ++j) {
                Ap[j] = acc[j];
                dp = fmaf(pr[j], Ap[j], dp);
            }
        }
        float pAp   = allreduce_bar(slots, 2u * it + 2u, dp, red, &bc, tid, bid);
        float alpha = rTr / pAp;

        // phase 4: update x, r (regs); publish border strip {r_new, p}
        float dr = 0.f;
        #pragma unroll
        for (int j = 0; j < 8; ++j) {
            xr[j] = fmaf(alpha, pr[j], xr[j]);
            rr[j] = fmaf(-alpha, Ap[j], rr[j]);
            if (strip[j]) {
                unsigned long long u = (unsigned long long)__float_as_uint(rr[j])
                                     | ((unsigned long long)__float_as_uint(pr[j]) << 32);
                __hip_atomic_store(&Hc[gy * W + gx0 + j], u,
                                   __ATOMIC_RELAXED, __HIP_MEMORY_SCOPE_AGENT);
            }
            dr = fmaf(rr[j], rr[j], dr);
        }
        float s = allreduce_bar(slots, 2u * it + 3u, dr, red, &bc, tid, bid);
        beta = s / rTr;
        rTr  = s;
    }

    // write x
    float* outc = out + ch * H * W;
    #pragma unroll
    for (int j = 0; j < 8; ++j) outc[gy * W + gx0 + j] = xr[j];
}

// ---------------------------------------------------------------------------
extern "C" void kernel_launch(void* const* d_in, const int* in_sizes, int n_in,
                              void* d_out, int out_size, void* d_ws, size_t ws_size,
                              hipStream_t stream)
{
    (void)in_sizes; (void)n_in; (void)out_size; (void)ws_size;
    const float* img  = (const float*)d_in[0];   // [3,512,512]
    const float* kern = (const float*)d_in[1];   // [11,11]
    const float* wts  = (const float*)d_in[2];   // [2]
    const float* gk   = (const float*)d_in[3];   // [2,3,3]
    float* out = (float*)d_out;
    float* ws  = (float*)d_ws;

    slot_init<<<1, 512, 0, stream>>>((unsigned long long*)ws);
    deconv_cg<<<dim3(NBLK), dim3(NTHR), 0, stream>>>(img, kern, wts, gk, out, ws);
}

// Round 4
// 3980.029 us; speedup vs baseline: 4.6178x; 1.2140x over previous
//
#include <hip/hip_runtime.h>

// ---------------------------------------------------------------------------
// DeconvCG: 100 CG iterations solving (K^T K + sum w_i^2 G_i^T G_i) x = K^T y
// Persistent-kernel design: 192 blocks (3ch x 8x8 tiles of 64x64), 512 thr.
// x, r, p in registers; p-halo + conv intermediate in LDS.
// Cross-block traffic: r-only 4B strips (coalesced), agent-scope relaxed
// atomics. Neighbor p' maintained locally via the identical beta-recurrence
// on a persistent LDS frame buffer F (bitwise-equal to owner's value).
// Grid barrier fused with dot allreduce: tagged slots, parity double-buffered.
// R4 fix: frame-map right band offset c+64 (was c+54: raced owned cells and
// left stale right-halo values -> absmax 49).
// ---------------------------------------------------------------------------

static constexpr int H = 512, W = 512, CCH = 3;
static constexpr int NPIX = CCH * H * W;
static constexpr int TDIM = 64;
static constexpr int RAD = 5;
static constexpr int HALO = 10;
static constexpr int PR = TDIM + 2 * HALO;        // 84
static constexpr int PSTR = PR + 1;               // 85
static constexpr int TR = TDIM + 2 * RAD;         // 74
static constexpr int TSTR = TR + 1;               // 75
static constexpr int NBLK = CCH * 8 * 8;          // 192
static constexpr int NTHR = 512;
static constexpr int NITER = 100;
static constexpr int FRN = 2960;                  // frame pixels (84^2-64^2)
static constexpr int SPN = 2160;                  // strip pixels (64^2-44^2)

// ---------------- block reduction (deterministic) --------------------------
__device__ __forceinline__ float block_reduce0(float v, float* red, int tid)
{
    __syncthreads();
    #pragma unroll
    for (int m = 32; m; m >>= 1) v += __shfl_xor(v, m, 64);
    if ((tid & 63) == 0) red[tid >> 6] = v;
    __syncthreads();
    float s = 0.f;
    if (tid == 0) {
        #pragma unroll
        for (int i = 0; i < NTHR / 64; ++i) s += red[i];
    }
    return s;          // valid on tid 0 only
}

// ---------------- fused grid-barrier + allreduce ---------------------------
__device__ __forceinline__ float allreduce_bar(unsigned long long* slots, unsigned seq,
                                               float thread_partial,
                                               float* red, float* bc, int tid, int bid)
{
    float part = block_reduce0(thread_partial, red, tid);
    asm volatile("s_waitcnt vmcnt(0)" ::: "memory");   // drain my strip stores/loads
    __syncthreads();
    unsigned long long* buf = slots + (size_t)(seq & 1u) * 256;
    if (tid == 0) {
        unsigned long long u = ((unsigned long long)seq << 32)
                             | (unsigned long long)__float_as_uint(part);
        __hip_atomic_store(&buf[bid], u, __ATOMIC_RELAXED, __HIP_MEMORY_SCOPE_AGENT);
    }
    float mine = 0.f;
    if (tid < NBLK) {
        unsigned long long v;
        for (;;) {
            v = __hip_atomic_load(&buf[tid], __ATOMIC_RELAXED, __HIP_MEMORY_SCOPE_AGENT);
            if ((unsigned)(v >> 32) == seq) break;
            __builtin_amdgcn_s_sleep(1);
        }
        mine = __uint_as_float((unsigned)v);
    }
    float s = block_reduce0(mine, red, tid);
    if (tid == 0) *bc = s;
    __syncthreads();
    return *bc;        // bitwise-identical in every block
}

// ---------------- 11x11 convs ----------------------------------------------
__device__ __forceinline__ void conv_fwd_phase(const float* __restrict__ kern,
                                               const float* __restrict__ P_,
                                               float* __restrict__ T_,
                                               int by0, int bx0, int tid)
{
    for (int seg = tid; seg < TR * 10; seg += NTHR) {
        int ry  = seg / 10;
        int rx0 = (seg - ry * 10) << 3;
        int gy  = by0 - RAD + ry;
        bool rowIn = (gy >= 0 && gy < H);
        float acc[8];
        #pragma unroll
        for (int j = 0; j < 8; ++j) acc[j] = 0.f;
        for (int a = 0; a < 11; ++a) {
            const float* row = P_ + (ry + a) * PSTR + rx0;
            float v[18];
            #pragma unroll
            for (int b = 0; b < 18; ++b) v[b] = row[b];
            #pragma unroll
            for (int b = 0; b < 11; ++b) {
                float kw = kern[a * 11 + b];
                #pragma unroll
                for (int j = 0; j < 8; ++j) acc[j] = fmaf(v[b + j], kw, acc[j]);
            }
        }
        #pragma unroll
        for (int j = 0; j < 8; ++j) {
            int rx = rx0 + j;
            if (rx < TR) {
                int gx = bx0 - RAD + rx;
                bool in = rowIn && gx >= 0 && gx < W;
                T_[ry * TSTR + rx] = in ? acc[j] : 0.f;   // zero outside image
            }
        }
    }
}

__device__ __forceinline__ void conv11_flip_acc(const float* __restrict__ src, int stride,
                                                int row0, int col0,
                                                const float* __restrict__ kern,
                                                float acc[8])
{
    for (int a = 0; a < 11; ++a) {
        const float* row = src + (row0 + a) * stride + col0;
        float v[18];
        #pragma unroll
        for (int b = 0; b < 18; ++b) v[b] = row[b];
        #pragma unroll
        for (int b = 0; b < 11; ++b) {
            float kw = kern[(10 - a) * 11 + (10 - b)];
            #pragma unroll
            for (int j = 0; j < 8; ++j) acc[j] = fmaf(v[b + j], kw, acc[j]);
        }
    }
}

// ---------------- regularizer term -----------------------------------------
__device__ __forceinline__ void reg_acc(const float* __restrict__ P_,
                                        const float* __restrict__ CB_,
                                        const float* __restrict__ gk,
                                        float w0sq, float w1sq,
                                        int oy, int ox0, int gy, int gx0,
                                        float acc[8])
{
    bool interior = (gy >= 1 && gy < H - 1 && gx0 >= 1 && gx0 <= W - 9);
    if (interior) {
        for (int a = 0; a < 5; ++a) {
            const float* row = P_ + (oy + 8 + a) * PSTR + ox0 + 8;
            float v[12];
            #pragma unroll
            for (int b = 0; b < 12; ++b) v[b] = row[b];
            #pragma unroll
            for (int b = 0; b < 5; ++b) {
                float cb = CB_[a * 5 + b];
                #pragma unroll
                for (int j = 0; j < 8; ++j) acc[j] = fmaf(v[b + j], cb, acc[j]);
            }
        }
    } else {
        for (int j = 0; j < 8; ++j) {
            int gx = gx0 + j;
            float racc = 0.f;
            for (int dy = -1; dy <= 1; ++dy)
                for (int dx = -1; dx <= 1; ++dx) {
                    int qy = gy + dy, qx = gx + dx;
                    if (qy >= 0 && qy < H && qx >= 0 && qx < W) {
                        float u0 = 0.f, u1 = 0.f;
                        int pr0 = oy + 10 + dy - 1, pc0 = ox0 + j + 10 + dx - 1;
                        for (int sy = 0; sy < 3; ++sy)
                            for (int sx = 0; sx < 3; ++sx) {
                                float pv = P_[(pr0 + sy) * PSTR + pc0 + sx];
                                u0 = fmaf(pv, gk[sy * 3 + sx], u0);
                                u1 = fmaf(pv, gk[9 + sy * 3 + sx], u1);
                            }
                        racc += w0sq * gk[(1 - dy) * 3 + (1 - dx)] * u0
                              + w1sq * gk[9 + (1 - dy) * 3 + (1 - dx)] * u1;
                    }
                }
            acc[j] += racc;
        }
    }
}

// ---------------- slot init (fresh tags each call) -------------------------
__global__ void slot_init(unsigned long long* slots) { slots[threadIdx.x] = 0ull; }

// ---------------- main persistent kernel -----------------------------------
__global__ void __launch_bounds__(NTHR)
deconv_cg(const float* __restrict__ img, const float* __restrict__ kern,
          const float* __restrict__ wts, const float* __restrict__ gk,
          float* __restrict__ out, float* __restrict__ ws)
{
    __shared__ float P[PR * PSTR];        // p (halo region); 0 outside image
    __shared__ float T[TR * TSTR + 32];   // conv intermediate / r staging
    __shared__ float F[FRN];              // persistent frame p' (recurrence)
    __shared__ float CB[25];
    __shared__ float red[NTHR / 64];
    __shared__ float bc;

    const int tid = threadIdx.x;
    const int bid = blockIdx.x;
    const int ch  = bid / 64;
    const int tt  = bid - ch * 64;
    const int by0 = (tt >> 3) * TDIM;
    const int bx0 = (tt & 7) * TDIM;

    const float* imgc = img + ch * H * W;
    unsigned long long* slots = (unsigned long long*)ws;   // [2][256] u64
    float* Hr = ws + 1024;                                 // published r (image layout)
    float* Hc = Hr + (size_t)ch * H * W;

    const float w0 = wts[0], w1 = wts[1];
    const float w0sq = w0 * w0, w1sq = w1 * w1;

    if (tid < 25) {
        int ty = tid / 5 - 2, tx = tid % 5 - 2;
        float s = 0.f;
        for (int ay = 0; ay < 3; ++ay)
            for (int ax = 0; ax < 3; ++ax) {
                int by_ = ay + ty, bx_ = ax + tx;
                if (by_ >= 0 && by_ < 3 && bx_ >= 0 && bx_ < 3)
                    s += w0sq * gk[ay * 3 + ax] * gk[by_ * 3 + bx_]
                       + w1sq * gk[9 + ay * 3 + ax] * gk[9 + by_ * 3 + bx_];
            }
        CB[tid] = s;
    }

    // owned-pixel mapping: thread -> 8 consecutive-x pixels of one row
    const int oy  = tid >> 3;
    const int ox0 = (tid & 7) << 3;
    const int gy  = by0 + oy;
    const int gx0 = bx0 + ox0;

    // ---- precomputed frame map (iteration-invariant): 6 slots/thread ------
    // frame = P-region [84x84] minus owned [10,74)x[10,74):
    //   rows 0..9 (840), rows 74..83 (840), rows 10..73 x cols {0..9, 74..83}
    int fP[6], fG[6];
    #pragma unroll
    for (int k = 0; k < 6; ++k) {
        int idx = tid + k * NTHR;
        fP[k] = -1; fG[k] = -1;
        if (idx < FRN) {
            int py, px;
            if (idx < 840)       { py = idx / 84;              px = idx - py * 84; }
            else if (idx < 1680) { int t = idx - 840;  py = 74 + t / 84; px = t - (t / 84) * 84; }
            else                 { int t = idx - 1680; py = 10 + t / 20;
                                   int c = t - (t / 20) * 20;  px = (c < 10) ? c : (c + 64); }
            int iy = by0 - HALO + py, ix = bx0 - HALO + px;
            if (iy >= 0 && iy < H && ix >= 0 && ix < W) {
                fP[k] = py * PSTR + px;
                fG[k] = iy * W + ix;
            }
        }
    }
    // ---- precomputed strip publish map: 5 slots/thread ---------------------
    // strip = owned-tile border width 10: rows 0..9, rows 54..63 (all cols),
    // rows 10..53 x cols {0..9, 54..63}
    int pT[5], pG[5];
    #pragma unroll
    for (int k = 0; k < 5; ++k) {
        int idx = tid + k * NTHR;
        pT[k] = -1; pG[k] = 0;
        if (idx < SPN) {
            int sy, sx;
            if (idx < 640)       { sy = idx >> 6;              sx = idx & 63; }
            else if (idx < 1280) { int t = idx - 640;  sy = 54 + (t >> 6); sx = t & 63; }
            else                 { int t = idx - 1280; sy = 10 + t / 20;
                                   int c = t - (t / 20) * 20;  sx = (c < 10) ? c : (c + 44); }
            pT[k] = sy * TSTR + sx;
            pG[k] = (by0 + sy) * W + bx0 + sx;
        }
    }

    float xr[8], rr[8], pr[8];

    // zero persistent frame buffer (beta=0 first iter: fmaf(0, F, r) needs F finite)
    for (int idx = tid; idx < FRN; idx += NTHR) F[idx] = 0.f;

    // ================= init: r0 = K^T y - A*x0, x0 = image, p0 = r0 ========
    for (int idx = tid; idx < PR * PR; idx += NTHR) {
        int py = idx / PR, px = idx - py * PR;
        int iy = by0 - HALO + py, ix = bx0 - HALO + px;
        float v = 0.f;
        if (iy >= 0 && iy < H && ix >= 0 && ix < W) v = imgc[iy * W + ix];
        P[py * PSTR + px] = v;
    }
    __syncthreads();
    conv_fwd_phase(kern, P, T, by0, bx0, tid);
    __syncthreads();
    float rTr, beta = 0.f;
    {
        float accA[8], accB[8];
        #pragma unroll
        for (int j = 0; j < 8; ++j) { accA[j] = 0.f; accB[j] = 0.f; }
        conv11_flip_acc(T, TSTR, oy, ox0, kern, accA);            // K^T K x0
        conv11_flip_acc(P, PSTR, oy + 5, ox0 + 5, kern, accB);    // b = K^T y
        reg_acc(P, CB, gk, w0sq, w1sq, oy, ox0, gy, gx0, accA);   // + reg x0
        float dr = 0.f;
        #pragma unroll
        for (int j = 0; j < 8; ++j) {
            float r0 = accB[j] - accA[j];
            rr[j] = r0;  pr[j] = r0;
            xr[j] = P[(oy + HALO) * PSTR + ox0 + HALO + j];
            dr = fmaf(r0, r0, dr);
        }
        __syncthreads();                         // everyone done reading T
        #pragma unroll
        for (int j = 0; j < 8; ++j) T[oy * TSTR + ox0 + j] = rr[j];
        __syncthreads();
        #pragma unroll
        for (int k = 0; k < 5; ++k)
            if (pT[k] >= 0)
                __hip_atomic_store(&Hc[pG[k]], T[pT[k]],
                                   __ATOMIC_RELAXED, __HIP_MEMORY_SCOPE_AGENT);
        rTr = allreduce_bar(slots, 1u, dr, red, &bc, tid, bid);
    }

    // ================= CG main loop ========================================
    for (int it = 0; it < NITER; ++it) {
        // phase 1: p = r + beta*p. Own tile from regs; frame via recurrence
        // F_new = fmaf(beta, F_old, r_neighbor) == neighbor's own pr value.
        #pragma unroll
        for (int j = 0; j < 8; ++j) pr[j] = fmaf(beta, pr[j], rr[j]);
        float fv[6];
        #pragma unroll
        for (int k = 0; k < 6; ++k)
            fv[k] = (fG[k] >= 0)
                  ? __hip_atomic_load(&Hc[fG[k]], __ATOMIC_RELAXED, __HIP_MEMORY_SCOPE_AGENT)
                  : 0.f;
        #pragma unroll
        for (int k = 0; k < 6; ++k)
            if (fG[k] >= 0) {
                int fi = tid + k * NTHR;
                float f = fmaf(beta, F[fi], fv[k]);
                F[fi] = f;
                P[fP[k]] = f;
            }
        #pragma unroll
        for (int j = 0; j < 8; ++j)
            P[(oy + HALO) * PSTR + ox0 + HALO + j] = pr[j];
        __syncthreads();

        // phase 2: t = conv(p, k)
        conv_fwd_phase(kern, P, T, by0, bx0, tid);
        __syncthreads();

        // phase 3: Ap on owned tile, dot(p,Ap)
        float Ap[8];
        float dp = 0.f;
        {
            float acc[8];
            #pragma unroll
            for (int j = 0; j < 8; ++j) acc[j] = 0.f;
            conv11_flip_acc(T, TSTR, oy, ox0, kern, acc);
            reg_acc(P, CB, gk, w0sq, w1sq, oy, ox0, gy, gx0, acc);
            #pragma unroll
            for (int j = 0; j < 8; ++j) {
                Ap[j] = acc[j];
                dp = fmaf(pr[j], Ap[j], dp);
            }
        }
        float pAp   = allreduce_bar(slots, 2u * it + 2u, dp, red, &bc, tid, bid);
        float alpha = rTr / pAp;

        // phase 4: update x, r; stage r in T; coalesced strip publish
        float dr = 0.f;
        #pragma unroll
        for (int j = 0; j < 8; ++j) {
            xr[j] = fmaf(alpha, pr[j], xr[j]);
            rr[j] = fmaf(-alpha, Ap[j], rr[j]);
            T[oy * TSTR + ox0 + j] = rr[j];
            dr = fmaf(rr[j], rr[j], dr);
        }
        __syncthreads();
        #pragma unroll
        for (int k = 0; k < 5; ++k)
            if (pT[k] >= 0)
                __hip_atomic_store(&Hc[pG[k]], T[pT[k]],
                                   __ATOMIC_RELAXED, __HIP_MEMORY_SCOPE_AGENT);
        float s = allreduce_bar(slots, 2u * it + 3u, dr, red, &bc, tid, bid);
        beta = s / rTr;
        rTr  = s;
    }

    // write x
    float* outc = out + ch * H * W;
    #pragma unroll
    for (int j = 0; j < 8; ++j) outc[gy * W + gx0 + j] = xr[j];
}

// ---------------------------------------------------------------------------
extern "C" void kernel_launch(void* const* d_in, const int* in_sizes, int n_in,
                              void* d_out, int out_size, void* d_ws, size_t ws_size,
                              hipStream_t stream)
{
    (void)in_sizes; (void)n_in; (void)out_size; (void)ws_size;
    const float* img  = (const float*)d_in[0];   // [3,512,512]
    const float* kern = (const float*)d_in[1];   // [11,11]
    const float* wts  = (const float*)d_in[2];   // [2]
    const float* gk   = (const float*)d_in[3];   // [2,3,3]
    float* out = (float*)d_out;
    float* ws  = (float*)d_ws;

    slot_init<<<1, 512, 0, stream>>>((unsigned long long*)ws);
    deconv_cg<<<dim3(NBLK), dim3(NTHR), 0, stream>>>(img, kern, wts, gk, out, ws);
}